// Round 2
// baseline (465.951 us; speedup 1.0000x reference)
//
#include <hip/hip_runtime.h>
#include <hip/hip_bf16.h>

// B=8, R=8, N=1024, D_IN=D_OUT=256, all fp32 in/out.
// prep_w : Wt[r][e][d] = bf16(W[r][d][e])         (scratch: first 1 MB of d_out, pre-memset)
// stage 1: sup[b,r,e,n] = bf16(x@W + bias)         (ws, 32 MB)
// stage 2: out[b,m,e] += adj[b,r,m,n]*sup[b,r,e,n]  (bf16 MFMA, split-K=8, atomicAdd)
// stage 3: ReLU in place.
//
// R5: fp32 operands (adj/x) VGPR-staged + cvt into PITCH-40 LDS (2-way banks free).
// Double-buffered LDS, ONE barrier/iter; next-iter loads issued AFTER the barrier.
// gemm grid: e2-pair blocks differ by 8 in linear index -> same XCD -> adj tile L2-shared.
//
// R6 (FAILED): launch_bounds (256,3) to kill suspected spills -> 461us (was 450). No spills
// existed; reverted to (256,4).
//
// R7: bf16 operands (sup in gemm, Wt in support) now staged via global_load_lds DMA into a
// LINEAR [128][32]-short buffer. The old session's DMA attempt hit 8/16-way read conflicts;
// fix per rule #21/m173: pre-swizzle the per-lane GLOBAL source chunk ((l&3)^((l>>3)&3)) so
// the linear DMA write lands data XOR-swizzled, and read frags at chunk (quad^((l16>>1)&3)).
// Read-side start bank = 16*r + 4*(quad^((r>>1)&3)) mod 32 -> 8 distinct b128 spans / 16
// lanes -> 2-way = free. Drops 2 loads + 2 ds_writes + ~8 VGPRs per iter per kernel.

#define Rr 8
#define Nn 1024
#define Dd 256
#define PITCH 40
#define BP 32

typedef __attribute__((ext_vector_type(8))) short short8;
typedef __attribute__((ext_vector_type(4))) float f32x4;

__device__ __forceinline__ short f2bf(float f) {
    unsigned u = __builtin_bit_cast(unsigned, f);
    u += 0x7fffu + ((u >> 16) & 1u);   // RNE
    return (short)(u >> 16);
}

__device__ __forceinline__ void dma16(const void* g, void* l) {
    __builtin_amdgcn_global_load_lds(
        (const __attribute__((address_space(1))) unsigned*)g,
        (__attribute__((address_space(3))) unsigned*)l, 16, 0, 0);
}

// ---------------- prep: Wt[r][e][d] bf16 <- W[r][d][e] f32 ----------------
__global__ void prep_w_kernel(const float* __restrict__ W, short* __restrict__ Wt) {
    __shared__ short T[64][72];
    const int tid = threadIdx.x;
    const int et = blockIdx.x, dt = blockIdx.y, r = blockIdx.z;
    const float* Wr = W + ((size_t)r * Dd + dt * 64) * Dd + et * 64;
    #pragma unroll
    for (int i = 0; i < 4; ++i) {
        int idx = tid + i * 256;
        int d_l = idx >> 4;
        int e4  = (idx & 15) * 4;
        f32x4 v = *(const f32x4*)(Wr + d_l * Dd + e4);
        T[e4 + 0][d_l] = f2bf(v[0]);
        T[e4 + 1][d_l] = f2bf(v[1]);
        T[e4 + 2][d_l] = f2bf(v[2]);
        T[e4 + 3][d_l] = f2bf(v[3]);
    }
    __syncthreads();
    short* o = Wt + ((size_t)r * Dd + et * 64) * Dd + dt * 64;
    #pragma unroll
    for (int i = 0; i < 2; ++i) {
        int idx = tid + i * 256;
        *(short8*)(o + (idx >> 3) * Dd + (idx & 7) * 8) = *(const short8*)&T[idx >> 3][(idx & 7) * 8];
    }
}

// ---------------- Stage 1: sup[b,r,e,n] = bf16(Wt @ x^T + bias) ----------------
// grid (2 e_t, 8 n_t, 64 br), block 256 = 4 waves (2e x 2n), tile 128e x 128n, BK=32, 8 iters.
// A = Wt (bf16): DMA'd, swizzled-linear.  B = x (fp32): reg-staged + cvt, PITCH 40.
__global__ __launch_bounds__(256, 4) void support_kernel(
        const float* __restrict__ x, const short* __restrict__ Wt,
        const float* __restrict__ bias, short* __restrict__ sup) {
    __shared__ short As[2][128 * BP];      // [e][d] bf16, linear, source-swizzled
    __shared__ short Bs[2][128 * PITCH];   // [n][d] bf16, cvt from fp32 x

    const int tid = threadIdx.x;
    const int wave = tid >> 6, lane = tid & 63;
    const int quad = lane >> 4, l16 = lane & 15;
    const int e_t = blockIdx.x, n_t = blockIdx.y, br = blockIdx.z;
    const int b = br >> 3, r = br & 7;
    const int we = wave & 1, wn = wave >> 1;

    const short* wp = Wt + ((size_t)r * Dd + e_t * 128) * Dd;
    const float* xb = x + ((size_t)b * Nn + n_t * 128) * Dd;

    // DMA source pattern: issue iss covers e-rows [wave*32+iss*16, +16); lane l fetches
    // row rbase+(l>>2), logical chunk ((l&3)^((l>>3)&3)) -> lands XOR-swizzled in linear LDS.
    const int drow = wave * 32 + (lane >> 2);
    const int lc   = ((lane & 3) ^ ((lane >> 3) & 3)) * 8;   // shorts
    auto dmaA = [&](int buf, int d0) {
        #pragma unroll
        for (int iss = 0; iss < 2; ++iss) {
            const short* g = wp + (size_t)(drow + iss * 16) * Dd + d0 + lc;
            dma16(g, (void*)&As[buf][(wave * 32 + iss * 16) * BP]);
        }
    };

    f32x4 xv[4];
    auto gload = [&](int d0) {
        #pragma unroll
        for (int i = 0; i < 2; ++i) {
            int idx = tid + i * 256;
            const float* p = xb + (idx >> 2) * Dd + d0 + (idx & 3) * 8;
            xv[2 * i]     = *(const f32x4*)p;
            xv[2 * i + 1] = *(const f32x4*)(p + 4);
        }
    };
    auto stage = [&](int buf) {
        #pragma unroll
        for (int i = 0; i < 2; ++i) {
            int idx = tid + i * 256;
            short8 t;
            t[0] = f2bf(xv[2 * i][0]); t[1] = f2bf(xv[2 * i][1]);
            t[2] = f2bf(xv[2 * i][2]); t[3] = f2bf(xv[2 * i][3]);
            t[4] = f2bf(xv[2 * i + 1][0]); t[5] = f2bf(xv[2 * i + 1][1]);
            t[6] = f2bf(xv[2 * i + 1][2]); t[7] = f2bf(xv[2 * i + 1][3]);
            *(short8*)&Bs[buf][(idx >> 2) * PITCH + (idx & 3) * 8] = t;
        }
    };

    const int bsw = (l16 >> 1) & 3;   // read-side chunk swizzle for linear A
    f32x4 acc[4][4] = {};
    dmaA(0, 0);
    gload(0);
    for (int it = 0; it < 8; ++it) {
        const int buf = it & 1;
        stage(buf);
        __syncthreads();   // vmcnt(0) drain completes DMA(buf)
        if (it < 7) { dmaA(buf ^ 1, (it + 1) * 32); gload((it + 1) * 32); }
        short8 a[4], bfr[4];
        #pragma unroll
        for (int i = 0; i < 4; ++i)
            a[i] = *(const short8*)&As[buf][(we * 64 + i * 16 + l16) * BP + (quad ^ bsw) * 8];
        #pragma unroll
        for (int j = 0; j < 4; ++j)
            bfr[j] = *(const short8*)&Bs[buf][(wn * 64 + j * 16 + l16) * PITCH + quad * 8];
        #pragma unroll
        for (int i = 0; i < 4; ++i)
            #pragma unroll
            for (int j = 0; j < 4; ++j)
                acc[i][j] = __builtin_amdgcn_mfma_f32_16x16x32_bf16(a[i], bfr[j], acc[i][j], 0, 0, 0);
    }

    // Epilogue: C[row=e][col=n]; add bias; bf16 store to sup[(b,r),e,n].
    #pragma unroll
    for (int i = 0; i < 4; ++i)
        #pragma unroll
        for (int reg = 0; reg < 4; ++reg) {
            int e = e_t * 128 + we * 64 + i * 16 + quad * 4 + reg;
            float bv = bias[r * Dd + e];
            #pragma unroll
            for (int j = 0; j < 4; ++j) {
                int n = n_t * 128 + wn * 64 + j * 16 + l16;
                sup[(((b * Rr + r) * Dd + e) << 10) + n] = f2bf(acc[i][j][reg] + bv);
            }
        }
}

// ---------------- Stage 2: out += adj @ sup^T (split-K=8) ----------------
// grid (16, 8, 8); bx: r = bx&7, e2 = bx>>3 -> e2-pairs differ by 8 -> same XCD (L2-share adj).
// block 256 = 4 waves (2m x 2e), tile 128m x 128e, BK=32, 32 iters.
// A = adj (fp32): reg-staged + cvt, PITCH 40.  B = sup (bf16): DMA'd, swizzled-linear.
__global__ __launch_bounds__(256, 4) void gcn_gemm_kernel(
        const float* __restrict__ adj, const short* __restrict__ sup,
        float* __restrict__ out) {
    __shared__ short Aa[2][128 * PITCH];   // [m][k] bf16 (cvt from fp32 adj)
    __shared__ short Bs[2][128 * BP];      // [e][k] bf16, linear, source-swizzled

    const int tid = threadIdx.x;
    const int wave = tid >> 6, lane = tid & 63;
    const int quad = lane >> 4, l16 = lane & 15;
    const int r = blockIdx.x & 7, e2 = blockIdx.x >> 3;
    const int m_t = blockIdx.y, b = blockIdx.z;
    const int wm = wave >> 1, we = wave & 1;

    const float* ap = adj + ((size_t)((b * Rr + r) * Nn + m_t * 128)) * Nn;
    const short* bp = sup + (((size_t)((b * Rr + r) * Dd + e2 * 128)) << 10);

    const int drow = wave * 32 + (lane >> 2);
    const int lc   = ((lane & 3) ^ ((lane >> 3) & 3)) * 8;   // shorts
    auto dmaB = [&](int buf, int kk) {
        #pragma unroll
        for (int iss = 0; iss < 2; ++iss) {
            const short* g = bp + ((size_t)(drow + iss * 16) << 10) + kk + lc;
            dma16(g, (void*)&Bs[buf][(wave * 32 + iss * 16) * BP]);
        }
    };

    f32x4 av[4];
    auto gload = [&](int kk) {
        #pragma unroll
        for (int i = 0; i < 2; ++i) {
            int idx = tid + i * 256;
            const float* p = ap + (size_t)(idx >> 2) * Nn + kk + (idx & 3) * 8;
            av[2 * i]     = *(const f32x4*)p;
            av[2 * i + 1] = *(const f32x4*)(p + 4);
        }
    };
    auto stage = [&](int buf) {
        #pragma unroll
        for (int i = 0; i < 2; ++i) {
            int idx = tid + i * 256;
            short8 t;
            t[0] = f2bf(av[2 * i][0]); t[1] = f2bf(av[2 * i][1]);
            t[2] = f2bf(av[2 * i][2]); t[3] = f2bf(av[2 * i][3]);
            t[4] = f2bf(av[2 * i + 1][0]); t[5] = f2bf(av[2 * i + 1][1]);
            t[6] = f2bf(av[2 * i + 1][2]); t[7] = f2bf(av[2 * i + 1][3]);
            *(short8*)&Aa[buf][(idx >> 2) * PITCH + (idx & 3) * 8] = t;
        }
    };

    const int bsw = (l16 >> 1) & 3;   // read-side chunk swizzle for linear B
    f32x4 acc[4][4] = {};
    dmaB(0, 0);
    gload(0);
    for (int it = 0; it < 32; ++it) {
        const int buf = it & 1;
        stage(buf);
        __syncthreads();   // vmcnt(0) drain completes DMA(buf)
        if (it < 31) { dmaB(buf ^ 1, (it + 1) * 32); gload((it + 1) * 32); }
        short8 a[4], bfr[4];
        #pragma unroll
        for (int i = 0; i < 4; ++i)
            a[i] = *(const short8*)&Aa[buf][(wm * 64 + i * 16 + l16) * PITCH + quad * 8];
        #pragma unroll
        for (int j = 0; j < 4; ++j)
            bfr[j] = *(const short8*)&Bs[buf][(we * 64 + j * 16 + l16) * BP + (quad ^ bsw) * 8];
        #pragma unroll
        for (int i = 0; i < 4; ++i)
            #pragma unroll
            for (int j = 0; j < 4; ++j)
                acc[i][j] = __builtin_amdgcn_mfma_f32_16x16x32_bf16(a[i], bfr[j], acc[i][j], 0, 0, 0);
    }

    // Epilogue: C[row=m][col=e]; split-K partial -> atomicAdd into zeroed out.
    float* ob = out + ((size_t)b * Nn + m_t * 128) * Dd + e2 * 128;
    #pragma unroll
    for (int i = 0; i < 4; ++i)
        #pragma unroll
        for (int reg = 0; reg < 4; ++reg) {
            int m_l = wm * 64 + i * 16 + quad * 4 + reg;
            #pragma unroll
            for (int j = 0; j < 4; ++j)
                atomicAdd(ob + (size_t)m_l * Dd + we * 64 + j * 16 + l16, acc[i][j][reg]);
        }
}

// ---------------- Stage 3: ReLU in place ----------------
__global__ void relu_kernel(float* __restrict__ out, int n4) {
    int i = blockIdx.x * blockDim.x + threadIdx.x;
    if (i < n4) {
        f32x4* p = (f32x4*)out;
        f32x4 v = p[i];
        v[0] = fmaxf(v[0], 0.f); v[1] = fmaxf(v[1], 0.f);
        v[2] = fmaxf(v[2], 0.f); v[3] = fmaxf(v[3], 0.f);
        p[i] = v;
    }
}

extern "C" void kernel_launch(void* const* d_in, const int* in_sizes, int n_in,
                              void* d_out, int out_size, void* d_ws, size_t ws_size,
                              hipStream_t stream) {
    const float* x    = (const float*)d_in[0];
    const float* adj  = (const float*)d_in[1];
    const float* W    = (const float*)d_in[2];
    const float* bias = (const float*)d_in[3];
    float* out = (float*)d_out;
    short* sup = (short*)d_ws;            // 32 MB of ws
    short* Wt  = (short*)d_out;           // 1 MB scratch inside d_out, consumed before memset

    prep_w_kernel<<<dim3(4, 4, 8), 256, 0, stream>>>(W, Wt);
    support_kernel<<<dim3(2, 8, 64), 256, 0, stream>>>(x, Wt, bias, sup);
    hipMemsetAsync(d_out, 0, (size_t)out_size * sizeof(float), stream);
    gcn_gemm_kernel<<<dim3(16, 8, 8), 256, 0, stream>>>(adj, sup, out);
    relu_kernel<<<(out_size / 4 + 255) / 256, 256, 0, stream>>>(out, out_size / 4);
}